// Round 8
// baseline (2685.647 us; speedup 1.0000x reference)
//
#include <hip/hip_runtime.h>
#include <hip/hip_bf16.h>

// Problem constants (fixed by the reference)
#define BB 1024
#define NN 512
#define MI 512
#define ME 16
#define ALPHA 0.05f
#define NS_ITERS 8   // Gershgorin c0 -> r~0.9; 0.9^256 ~ 7e-12: converged
#define ADMM_IT 15
#define NBLK 256     // persistent-kernel grid; 52KB LDS -> >=3 blocks/CU capacity (768>=256)

typedef __attribute__((ext_vector_type(8))) short short8;
typedef __attribute__((ext_vector_type(4))) float float4v;

__device__ inline short f2bf(float v) {
    __hip_bfloat16 b = __float2bfloat16(v);
    return *reinterpret_cast<short*>(&b);
}
__device__ inline float bf2f(short s) {
    __hip_bfloat16 b = *reinterpret_cast<__hip_bfloat16*>(&s);
    return __bfloat162float(b);
}
__device__ inline void split_store(float v, short* __restrict__ hi, short* __restrict__ lo, size_t idx) {
    short h = f2bf(v);
    hi[idx] = h;
    lo[idx] = f2bf(v - bf2f(h));
}

// ---- software grid barrier (monotonic counter, device-scope) ----
// Safe because grid (256 blocks) <= co-resident capacity (>=3 blocks/CU * 256 CUs).
__device__ __forceinline__ void gsync(unsigned* bar, unsigned& phase) {
    __syncthreads();
    ++phase;
    if (threadIdx.x == 0) {
        __threadfence();                       // release prior writes device-wide
        atomicAdd(bar, 1u);
        unsigned target = phase * (unsigned)NBLK;
        while (__hip_atomic_load(bar, __ATOMIC_RELAXED, __HIP_MEMORY_SCOPE_AGENT) < target) {
            __builtin_amdgcn_s_sleep(8);
        }
        __threadfence();                       // acquire
    }
    __syncthreads();
}

// ---------------- dtype auto-detect ----------------
__global__ void detect_dtype_k(const unsigned short* __restrict__ g_raw,
                               float* __restrict__ flag) {
    __shared__ int cnt;
    int tid = threadIdx.x;
    if (tid == 0) cnt = 0;
    __syncthreads();
    int local = 0;
    for (int i = tid; i < 8192; i += 256) {
        int e = (g_raw[i] >> 7) & 0xFF;
        if (e >= 0x83) local++;
    }
    atomicAdd(&cnt, local);
    __syncthreads();
    if (tid == 0) flag[0] = (cnt < 64) ? 1.0f : 0.0f;  // 1 => bf16 inputs
}

// ---------------- fused ingest (also zeroes barrier counters) ----------------
__global__ void ingest_all_k(const void* __restrict__ c_raw, const void* __restrict__ G_raw,
                             const void* __restrict__ h_raw, const void* __restrict__ A_raw,
                             const void* __restrict__ b_raw,
                             float* __restrict__ cF, short* __restrict__ xh, short* __restrict__ xl,
                             float* __restrict__ GF, short* __restrict__ GFh, short* __restrict__ GFl,
                             float* __restrict__ hF, float* __restrict__ AF, float* __restrict__ bF,
                             const float* __restrict__ flag,
                             unsigned* __restrict__ bar0, unsigned* __restrict__ bar1) {
    int i = blockIdx.x * 256 + threadIdx.x;
    if (blockIdx.x == 0 && threadIdx.x == 0) { bar0[0] = 0u; bar1[0] = 0u; }
    bool isbf = flag[0] > 0.5f;
    #define RD(p, idx) (isbf ? __bfloat162float(((const __hip_bfloat16*)(p))[idx]) : ((const float*)(p))[idx])
    if (i < BB * NN) { float v = RD(c_raw, i); cF[i] = v; split_store(v, xh, xl, i); }
    if (i < MI * NN) { float v = RD(G_raw, i); GF[i] = v; split_store(v, GFh, GFl, i); }
    if (i < MI)      hF[i] = RD(h_raw, i);
    if (i < ME * NN) AF[i] = RD(A_raw, i);
    if (i < ME)      bF[i] = RD(b_raw, i);
    #undef RD
}

// ---------------- split-bf16 MFMA NT tile worker, K = 512 ----------------
#define CH 128
#define LDC 136

template<int RH>
__device__ __forceinline__ void tile_nt(
    const short* __restrict__ Ahi, const short* __restrict__ Alo,
    const short* __restrict__ Bhi, const short* __restrict__ Blo,
    int m0, int n0, short* __restrict__ As, short* __restrict__ Bs,
    float4v* __restrict__ out)
{
    const int tid = threadIdx.x;
    const int wv = tid >> 6, ln = tid & 63;
    const int quad = ln >> 4, lr = ln & 15;
    constexpr int AV = RH * 2;
    constexpr int APL = RH * 16 * LDC;

    float4v acc1[RH], acc2[RH];
    #pragma unroll
    for (int h = 0; h < RH; ++h) {
        acc1[h] = (float4v){0.f, 0.f, 0.f, 0.f};
        acc2[h] = (float4v){0.f, 0.f, 0.f, 0.f};
    }

    short8 pa[AV], pb[8];
    #pragma unroll
    for (int i = 0; i < AV; ++i) {
        int s = tid + 256 * i;
        int pl = s / (RH * 256), rem = s % (RH * 256);
        int row = rem >> 4, oct = rem & 15;
        const short* P = pl ? Alo : Ahi;
        pa[i] = *(const short8*)(P + (size_t)(m0 + row) * 512 + oct * 8);
    }
    #pragma unroll
    for (int i = 0; i < 8; ++i) {
        int s = tid + 256 * i;
        int pl = s >> 10, rem = s & 1023;
        int row = rem >> 4, oct = rem & 15;
        const short* P = pl ? Blo : Bhi;
        pb[i] = *(const short8*)(P + (size_t)(n0 + row) * 512 + oct * 8);
    }

    for (int c = 0; c < 4; ++c) {
        __syncthreads();
        #pragma unroll
        for (int i = 0; i < AV; ++i) {
            int s = tid + 256 * i;
            int pl = s / (RH * 256), rem = s % (RH * 256);
            int row = rem >> 4, oct = rem & 15;
            *(short8*)&As[pl * APL + row * LDC + oct * 8] = pa[i];
        }
        #pragma unroll
        for (int i = 0; i < 8; ++i) {
            int s = tid + 256 * i;
            int pl = s >> 10, rem = s & 1023;
            int row = rem >> 4, oct = rem & 15;
            *(short8*)&Bs[pl * (64 * LDC) + row * LDC + oct * 8] = pb[i];
        }
        __syncthreads();
        if (c + 1 < 4) {
            int kb = (c + 1) * CH;
            #pragma unroll
            for (int i = 0; i < AV; ++i) {
                int s = tid + 256 * i;
                int pl = s / (RH * 256), rem = s % (RH * 256);
                int row = rem >> 4, oct = rem & 15;
                const short* P = pl ? Alo : Ahi;
                pa[i] = *(const short8*)(P + (size_t)(m0 + row) * 512 + kb + oct * 8);
            }
            #pragma unroll
            for (int i = 0; i < 8; ++i) {
                int s = tid + 256 * i;
                int pl = s >> 10, rem = s & 1023;
                int row = rem >> 4, oct = rem & 15;
                const short* P = pl ? Blo : Bhi;
                pb[i] = *(const short8*)(P + (size_t)(n0 + row) * 512 + kb + oct * 8);
            }
        }
        #pragma unroll
        for (int ks = 0; ks < 4; ++ks) {
            int ko = (ks * 4 + quad) * 8;
            short8 bh = *(const short8*)&Bs[(wv * 16 + lr) * LDC + ko];
            short8 bl = *(const short8*)&Bs[64 * LDC + (wv * 16 + lr) * LDC + ko];
            #pragma unroll
            for (int h = 0; h < RH; ++h) {
                short8 ah = *(const short8*)&As[(h * 16 + lr) * LDC + ko];
                short8 al = *(const short8*)&As[APL + (h * 16 + lr) * LDC + ko];
                acc1[h] = __builtin_amdgcn_mfma_f32_16x16x32_bf16(ah, bh, acc1[h], 0, 0, 0);
                acc2[h] = __builtin_amdgcn_mfma_f32_16x16x32_bf16(ah, bl, acc2[h], 0, 0, 0);
                acc2[h] = __builtin_amdgcn_mfma_f32_16x16x32_bf16(al, bh, acc2[h], 0, 0, 0);
            }
        }
    }
    #pragma unroll
    for (int h = 0; h < RH; ++h) out[h] = acc1[h] + acc2[h];
}

// ---------------- persistent precompute kernel (NS inverse + Schur + R/Q) ----
struct NsArgs {
    const float *GF, *AF, *bF;
    const short *GFh, *GFl;
    short *GTh, *GTl;
    float *Mm; short *Mmh, *Mml;
    float *rs, *c0s;
    float *X0; short *X0h, *X0l;
    float *X1; short *X1h, *X1l;
    short *Uh, *Ul;
    float *Y, *Sm, *Si, *T1, *zb, *g0, *Rf;
    short *Rh, *Rl, *W1h, *W1l, *RTh, *RTl, *Qh, *Ql;
    unsigned *bar;
};

__global__ __launch_bounds__(256) void ns_persist_k(NsArgs a) {
    __shared__ short smem[2 * 16 * LDC + 2 * 64 * LDC];
    short* As = smem;
    short* Bs = smem + 2 * 16 * LDC;
    unsigned phase = 0;
    const int blk = blockIdx.x, tid = threadIdx.x;
    const int wv = tid >> 6, ln = tid & 63;
    const int quad = ln >> 4, lr = ln & 15;
    const int m0 = (blk & 31) * 16, n0 = (blk >> 5) * 64;

    // A: G^T planes (transpose GF)
    {
        float (*tsh)[33] = (float(*)[33])smem;
        int bx = (blk & 15) * 32, by = (blk >> 4) * 32;
        int tx = tid & 31, ty0 = tid >> 5;
        for (int i = ty0; i < 32; i += 8) tsh[i][tx] = a.GF[(by + i) * 512 + bx + tx];
        __syncthreads();
        for (int i = ty0; i < 32; i += 8)
            split_store(tsh[tx][i], a.GTh, a.GTl, (size_t)(bx + i) * 512 + by + tx);
    }
    gsync(a.bar, phase);
    // B: M = I + G^T G (f32 + planes)
    {
        float4v out[1];
        tile_nt<1>(a.GTh, a.GTl, a.GTh, a.GTl, m0, n0, As, Bs, out);
        #pragma unroll
        for (int r = 0; r < 4; ++r) {
            int m = m0 + quad * 4 + r, n = n0 + wv * 16 + lr;
            size_t idx = (size_t)m * 512 + n;
            float v = out[0][r] + ((m == n) ? 1.f : 0.f);
            a.Mm[idx] = v;
            split_store(v, a.Mmh, a.Mml, idx);
        }
    }
    gsync(a.bar, phase);
    // C: row abs sums
    {
        int row = blk * 4 + wv;
        if (row < 512) {
            float s = 0.f;
            #pragma unroll
            for (int i = 0; i < 8; ++i) s += fabsf(a.Mm[(size_t)row * 512 + ln + i * 64]);
            for (int off = 32; off; off >>= 1) s += __shfl_down(s, off);
            if (ln == 0) a.rs[row] = s;
        }
    }
    gsync(a.bar, phase);
    // D: c0
    if (blk == 0 && wv == 0) {
        float m = 0.f;
        #pragma unroll
        for (int i = 0; i < 8; ++i) m = fmaxf(m, a.rs[ln + i * 64]);
        for (int off = 32; off; off >>= 1) m = fmaxf(m, __shfl_down(m, off));
        if (ln == 0) a.c0s[0] = 2.0f / (1.0f + m);
    }
    gsync(a.bar, phase);
    // E: X0 = c0 * I
    {
        float c0 = a.c0s[0];
        #pragma unroll
        for (int i = 0; i < 4; ++i) {
            int idx = blk * 1024 + i * 256 + tid;
            int r = idx >> 9, cc = idx & 511;
            float v = (r == cc) ? c0 : 0.f;
            a.X0[idx] = v;
            split_store(v, a.X0h, a.X0l, idx);
        }
    }
    gsync(a.bar, phase);
    // NS iterations
    float* Xf[2] = {a.X0, a.X1};
    short* Xh[2] = {a.X0h, a.X1h};
    short* Xl[2] = {a.X0l, a.X1l};
    int cur = 0;
    for (int itr = 0; itr < NS_ITERS; ++itr) {
        int nxt = cur ^ 1;
        {
            float4v out[1];
            tile_nt<1>(Xh[cur], Xl[cur], a.Mmh, a.Mml, m0, n0, As, Bs, out);
            #pragma unroll
            for (int r = 0; r < 4; ++r) {
                int m = m0 + quad * 4 + r, n = n0 + wv * 16 + lr;
                split_store(out[0][r], a.Uh, a.Ul, (size_t)m * 512 + n);
            }
        }
        gsync(a.bar, phase);
        {
            float4v out[1];
            tile_nt<1>(a.Uh, a.Ul, Xh[cur], Xl[cur], m0, n0, As, Bs, out);
            #pragma unroll
            for (int r = 0; r < 4; ++r) {
                int m = m0 + quad * 4 + r, n = n0 + wv * 16 + lr;
                size_t idx = (size_t)m * 512 + n;
                float v = 2.f * Xf[cur][idx] - out[0][r];
                Xf[nxt][idx] = v;
                split_store(v, Xh[nxt], Xl[nxt], idx);
            }
        }
        gsync(a.bar, phase);
        cur = nxt;
    }
    const float* Minv = a.X0;  // NS_ITERS even
    // Y = Minv A^T (512x16)
    {
        #pragma unroll
        for (int t = 0; t < 2; ++t) {
            int m = blk * 2 + t;
            float mv[8];
            #pragma unroll
            for (int i = 0; i < 8; ++i) mv[i] = Minv[(size_t)m * 512 + ln + i * 64];
            #pragma unroll
            for (int jj = 0; jj < 4; ++jj) {
                int j = wv * 4 + jj;
                float s = 0.f;
                #pragma unroll
                for (int i = 0; i < 8; ++i) s += mv[i] * a.AF[j * 512 + ln + i * 64];
                for (int off = 32; off; off >>= 1) s += __shfl_down(s, off);
                if (ln == 0) a.Y[m * 16 + j] = s;
            }
        }
    }
    gsync(a.bar, phase);
    // Sm = A Y (16x16)
    if (blk == 0) {
        int i = tid >> 4, j = tid & 15;
        float s = 0.f;
        #pragma unroll 8
        for (int k = 0; k < 512; ++k) s += a.AF[i * 512 + k] * a.Y[k * 16 + j];
        a.Sm[i * 16 + j] = s;
    }
    gsync(a.bar, phase);
    // Si = inv(Sm), Gauss-Jordan in one wave
    if (blk == 0 && wv == 0) {
        int r = ln;
        float av[16], bI[16];
        #pragma unroll
        for (int j = 0; j < 16; ++j) {
            av[j] = (r < 16) ? a.Sm[r * 16 + j] : 0.f;
            bI[j] = (r < 16 && j == r) ? 1.f : 0.f;
        }
        for (int k = 0; k < 16; ++k) {
            float pa[16], pb[16];
            #pragma unroll
            for (int j = 0; j < 16; ++j) { pa[j] = __shfl(av[j], k); pb[j] = __shfl(bI[j], k); }
            float inv = 1.0f / pa[k];
            if (r == k) {
                #pragma unroll
                for (int j = 0; j < 16; ++j) { av[j] = pa[j] * inv; bI[j] = pb[j] * inv; }
            } else {
                float f = av[k] * inv;
                #pragma unroll
                for (int j = 0; j < 16; ++j) {
                    av[j] = fmaf(-f, pa[j], av[j]);
                    bI[j] = fmaf(-f, pb[j], bI[j]);
                }
            }
        }
        if (r < 16)
            #pragma unroll
            for (int j = 0; j < 16; ++j) a.Si[r * 16 + j] = bI[j];
    }
    gsync(a.bar, phase);
    // T1 = Y Si; zb = T1 b
    if (blk < 32) {
        int m = blk * 16 + (tid >> 4), j = tid & 15;
        float s = 0.f;
        #pragma unroll
        for (int k = 0; k < 16; ++k) s += a.Y[m * 16 + k] * a.Si[k * 16 + j];
        a.T1[m * 16 + j] = s;
        float v = s * a.bF[j];
        v += __shfl_down(v, 8); v += __shfl_down(v, 4);
        v += __shfl_down(v, 2); v += __shfl_down(v, 1);
        if (j == 0) a.zb[m] = v;
    }
    gsync(a.bar, phase);
    // W1 = Minv - T1 Y^T -> planes
    {
        #pragma unroll
        for (int i = 0; i < 4; ++i) {
            int idx = blk * 1024 + i * 256 + tid;
            int m = idx >> 9, n = idx & 511;
            float s = Minv[idx];
            #pragma unroll
            for (int k = 0; k < 16; ++k) s -= a.T1[m * 16 + k] * a.Y[n * 16 + k];
            split_store(s, a.W1h, a.W1l, idx);
        }
    }
    gsync(a.bar, phase);
    // R = G W1 (f32 + planes; W1 symmetric)
    {
        float4v out[1];
        tile_nt<1>(a.GFh, a.GFl, a.W1h, a.W1l, m0, n0, As, Bs, out);
        #pragma unroll
        for (int r = 0; r < 4; ++r) {
            int m = m0 + quad * 4 + r, n = n0 + wv * 16 + lr;
            size_t idx = (size_t)m * 512 + n;
            a.Rf[idx] = out[0][r];
            split_store(out[0][r], a.Rh, a.Rl, idx);
        }
    }
    gsync(a.bar, phase);
    // Q = R G^T planes; RT planes; g0 = G zb
    {
        float4v out[1];
        tile_nt<1>(a.Rh, a.Rl, a.GFh, a.GFl, m0, n0, As, Bs, out);
        #pragma unroll
        for (int r = 0; r < 4; ++r) {
            int m = m0 + quad * 4 + r, n = n0 + wv * 16 + lr;
            split_store(out[0][r], a.Qh, a.Ql, (size_t)m * 512 + n);
        }
        __syncthreads();
        float (*tsh)[33] = (float(*)[33])smem;
        int bx = (blk & 15) * 32, by = (blk >> 4) * 32;
        int tx = tid & 31, ty0 = tid >> 5;
        for (int i = ty0; i < 32; i += 8) tsh[i][tx] = a.Rf[(by + i) * 512 + bx + tx];
        __syncthreads();
        for (int i = ty0; i < 32; i += 8)
            split_store(tsh[tx][i], a.RTh, a.RTl, (size_t)(bx + i) * 512 + by + tx);
        if (blk < 128) {
            int m = blk * 4 + wv;
            float s = 0.f;
            #pragma unroll
            for (int i = 0; i < 8; ++i) s += a.GF[(size_t)m * 512 + ln + i * 64] * a.zb[ln + i * 64];
            for (int off = 32; off; off >>= 1) s += __shfl_down(s, off);
            if (ln == 0) a.g0[m] = s;
        }
    }
}

// ---------------- persistent projection kernel (all 4 projections) ----------
struct ProjArgs {
    short *xh, *xl;
    const short *Bch, *Bcl;              // Bcat = [G; R; W1] planes (1536 x 512)
    const short *Qh, *Ql, *RTh, *RTl;
    const float *hF, *g0, *zb, *cF, *dtf;
    float *q0, *xW, *uB;
    short *tAh, *tAl, *tBh, *tBl;
    void *Out;
    unsigned *bar;
};

__global__ __launch_bounds__(256) void proj_persist_k(ProjArgs a) {
    __shared__ short smem[2 * 32 * LDC + 2 * 64 * LDC];
    short* As = smem;
    short* Bs = smem + 2 * 32 * LDC;
    unsigned phase = 0;
    const int tid = threadIdx.x;
    const int wv = tid >> 6, ln = tid & 63;
    const int quad = ln >> 4, lr = ln & 15;
    const int m0b = (blockIdx.x & 31) * 32, n0b = (blockIdx.x >> 5) * 64;

    for (int p = 0; p < 4; ++p) {
        // combo: x @ [G;R;W1]^T -> t0/u0 | q0 | xW  (768 tiles, 3 per block)
        for (int t = blockIdx.x; t < 768; t += 256) {
            int m0 = (t & 31) * 32, nc0 = (t >> 5) * 64;
            float4v out[2];
            tile_nt<2>(a.xh, a.xl, a.Bch, a.Bcl, m0, nc0, As, Bs, out);
            int seg = nc0 >> 9, nl0 = nc0 & 511;
            #pragma unroll
            for (int h = 0; h < 2; ++h) {
                #pragma unroll
                for (int r = 0; r < 4; ++r) {
                    int m = m0 + h * 16 + quad * 4 + r;
                    int nl = nl0 + wv * 16 + lr;
                    size_t idx = (size_t)m * 512 + nl;
                    float v = out[h][r];
                    if (seg == 0) {
                        float t0 = fminf(a.hF[nl], v);
                        a.uB[idx] = 0.f;
                        split_store(t0, a.tAh, a.tAl, idx);
                    } else if (seg == 1) {
                        a.q0[idx] = v + a.g0[nl];
                    } else {
                        a.xW[idx] = v;
                    }
                }
            }
        }
        gsync(a.bar, phase);
        // 15 ADMM steps
        for (int it = 0; it < ADMM_IT; ++it) {
            const short* sh = (it & 1) ? a.tBh : a.tAh;
            const short* sl = (it & 1) ? a.tBl : a.tAl;
            short* dh = (it & 1) ? a.tAh : a.tBh;
            short* dl = (it & 1) ? a.tAl : a.tBl;
            float4v out[2];
            tile_nt<2>(sh, sl, a.Qh, a.Ql, m0b, n0b, As, Bs, out);
            #pragma unroll
            for (int h = 0; h < 2; ++h) {
                #pragma unroll
                for (int r = 0; r < 4; ++r) {
                    int m = m0b + h * 16 + quad * 4 + r;
                    int n = n0b + wv * 16 + lr;
                    size_t idx = (size_t)m * 512 + n;
                    float w = a.hF[n] - (out[h][r] + a.q0[idx]) - a.uB[idx];
                    a.uB[idx] = fmaxf(0.f, -w);
                    split_store(a.hF[n] - fabsf(w), dh, dl, idx);
                }
            }
            gsync(a.bar, phase);
        }
        // final z = t R + xW + zb; PGD split or emit (t ends in tB after 15 iters)
        {
            float4v out[2];
            tile_nt<2>(a.tBh, a.tBl, a.RTh, a.RTl, m0b, n0b, As, Bs, out);
            #pragma unroll
            for (int h = 0; h < 2; ++h) {
                #pragma unroll
                for (int r = 0; r < 4; ++r) {
                    int m = m0b + h * 16 + quad * 4 + r;
                    int n = n0b + wv * 16 + lr;
                    size_t idx = (size_t)m * 512 + n;
                    float z = out[h][r] + a.xW[idx] + a.zb[n];
                    if (p < 3) {
                        split_store((1.0f - ALPHA) * z + ALPHA * a.cF[idx], a.xh, a.xl, idx);
                    } else {
                        if (a.dtf[0] > 0.5f) ((__hip_bfloat16*)a.Out)[idx] = __float2bfloat16(z);
                        else                 ((float*)a.Out)[idx] = z;
                    }
                }
            }
        }
        gsync(a.bar, phase);
    }
}

// ---------------- host launcher ----------------

extern "C" void kernel_launch(void* const* d_in, const int* in_sizes, int n_in,
                              void* d_out, int out_size, void* d_ws, size_t ws_size,
                              hipStream_t stream) {
    const void* c_raw = d_in[0];
    const void* G_raw = d_in[1];
    const void* h_raw = d_in[2];
    const void* A_raw = d_in[3];
    const void* b_raw = d_in[4];

    float* w = (float*)d_ws;
    size_t o = 0;
    auto alloc = [&](size_t n) { float* p = w + o; o += (n + 63) & ~(size_t)63; return p; };

    float* cF  = alloc(BB * NN);
    float* GF  = alloc(MI * NN);
    float* AF  = alloc(ME * NN);
    float* hF  = alloc(MI);
    float* bF  = alloc(ME);
    float* Mm  = alloc(NN * NN);
    float* Xf0 = alloc(NN * NN);
    float* Xf1 = alloc(NN * NN);
    float* Rf  = alloc(MI * NN);
    float* Y   = alloc(NN * ME);
    float* T1  = alloc(NN * ME);
    float* Sm  = alloc(ME * ME);
    float* Si  = alloc(ME * ME);
    float* zb  = alloc(NN);
    float* g0  = alloc(MI);
    float* rs  = alloc(NN);
    float* c0s = alloc(16);
    float* dtf = alloc(16);
    float* barf = alloc(32);
    float* q0  = alloc(BB * MI);
    float* xW  = alloc(BB * NN);
    float* uB  = alloc(BB * MI);
    unsigned* bar0 = (unsigned*)barf;
    unsigned* bar1 = (unsigned*)(barf + 16);

    short* sbp = (short*)(w + o);
    size_t so = 0;
    auto allocS = [&](size_t n) { short* p = sbp + so; so += (n + 127) & ~(size_t)127; return p; };

    short* Bcat_h = allocS(3 * 512 * 512);
    short* Bcat_l = allocS(3 * 512 * 512);
    short* GFh = Bcat_h;              short* GFl = Bcat_l;
    short* Rh  = Bcat_h + 512 * 512;  short* Rl  = Bcat_l + 512 * 512;
    short* W1h = Bcat_h + 1024 * 512; short* W1l = Bcat_l + 1024 * 512;

    short* GTh = allocS(NN * MI);  short* GTl = allocS(NN * MI);
    short* Mmh = allocS(NN * NN);  short* Mml = allocS(NN * NN);
    short* X0h = allocS(NN * NN);  short* X0l = allocS(NN * NN);
    short* X1h = allocS(NN * NN);  short* X1l = allocS(NN * NN);
    short* Uh  = allocS(NN * NN);  short* Ul  = allocS(NN * NN);
    short* RTh = allocS(NN * MI);  short* RTl = allocS(NN * MI);
    short* Qh  = allocS(MI * MI);  short* Ql  = allocS(MI * MI);
    short* xh  = allocS(BB * NN);  short* xl  = allocS(BB * NN);
    short* tAh = allocS(BB * MI);  short* tAl = allocS(BB * MI);
    short* tBh = allocS(BB * MI);  short* tBl = allocS(BB * MI);

    dim3 blk(256);
    auto cdiv = [](int a, int b) { return (a + b - 1) / b; };

    detect_dtype_k<<<1, 256, 0, stream>>>((const unsigned short*)G_raw, dtf);
    ingest_all_k<<<cdiv(BB * NN, 256), blk, 0, stream>>>(
        c_raw, G_raw, h_raw, A_raw, b_raw,
        cF, xh, xl, GF, GFh, GFl, hF, AF, bF, dtf, bar0, bar1);

    NsArgs na;
    na.GF = GF; na.AF = AF; na.bF = bF;
    na.GFh = GFh; na.GFl = GFl;
    na.GTh = GTh; na.GTl = GTl;
    na.Mm = Mm; na.Mmh = Mmh; na.Mml = Mml;
    na.rs = rs; na.c0s = c0s;
    na.X0 = Xf0; na.X0h = X0h; na.X0l = X0l;
    na.X1 = Xf1; na.X1h = X1h; na.X1l = X1l;
    na.Uh = Uh; na.Ul = Ul;
    na.Y = Y; na.Sm = Sm; na.Si = Si; na.T1 = T1; na.zb = zb; na.g0 = g0; na.Rf = Rf;
    na.Rh = Rh; na.Rl = Rl; na.W1h = W1h; na.W1l = W1l;
    na.RTh = RTh; na.RTl = RTl; na.Qh = Qh; na.Ql = Ql;
    na.bar = bar0;
    ns_persist_k<<<NBLK, blk, 0, stream>>>(na);

    ProjArgs pa;
    pa.xh = xh; pa.xl = xl;
    pa.Bch = Bcat_h; pa.Bcl = Bcat_l;
    pa.Qh = Qh; pa.Ql = Ql; pa.RTh = RTh; pa.RTl = RTl;
    pa.hF = hF; pa.g0 = g0; pa.zb = zb; pa.cF = cF; pa.dtf = dtf;
    pa.q0 = q0; pa.xW = xW; pa.uB = uB;
    pa.tAh = tAh; pa.tAl = tAl; pa.tBh = tBh; pa.tBl = tBl;
    pa.Out = d_out;
    pa.bar = bar1;
    proj_persist_k<<<NBLK, blk, 0, stream>>>(pa);
}